// Round 15
// baseline (344.742 us; speedup 1.0000x reference)
//
#include <hip/hip_runtime.h>
#include <math.h>

#define NR 131072
#define KC 1024
#define DD 256

// d_out element offsets (float32 elements)
#define ZQ_OFF  0
#define RES_OFF 33554432
#define IDX_OFF 67108864
#define LOSS_OFF 67239936
#define PERP_OFF 67239937

// ws byte offsets (total ~536 KB)
#define WS_CNT 0          // int[1024]
#define WS_C2N 4096       // float[1024]
#define WS_BSS 8192       // double[2048]
#define WS_CBS 24576      // ushort cbs hi-only: 64 tiles x 8KB = 512KB

#define MARG 5e-4f
#define CCAP 24

#define FM(x,y) __fmul_rn((x),(y))
#define FA(x,y) __fadd_rn((x),(y))

typedef __attribute__((ext_vector_type(8))) short bf16x8;
typedef __attribute__((ext_vector_type(4))) float f32x4;

static __device__ __forceinline__ unsigned short bf16h(float f) {
  unsigned int u = __float_as_uint(f);
  u += 0x7FFFu + ((u >> 16) & 1u);
  return (unsigned short)(u >> 16);
}

// async global->LDS, 16B/lane; LDS dest = wave-uniform base + lane*16
static __device__ __forceinline__ void glds16(const void* g, void* l) {
  __builtin_amdgcn_global_load_lds(
      (const __attribute__((address_space(1))) void*)g,
      (__attribute__((address_space(3))) void*)l, 16, 0, 0);
}

// ---- numpy f32 pairwise sum-of-squares, one 128-block (AVX512 tree) --------
static __device__ __forceinline__ float np_sumsq128(const float* __restrict__ q) {
  float lane[16];
#pragma unroll
  for (int l = 0; l < 16; l++) {
    float s0 = FM(q[l +   0], q[l +   0]);
    float s1 = FM(q[l +  16], q[l +  16]);
    float s2 = FM(q[l +  32], q[l +  32]);
    float s3 = FM(q[l +  48], q[l +  48]);
    float s4 = FM(q[l +  64], q[l +  64]);
    float s5 = FM(q[l +  80], q[l +  80]);
    float s6 = FM(q[l +  96], q[l +  96]);
    float s7 = FM(q[l + 112], q[l + 112]);
    lane[l] = FA(FA(FA(s0, s1), FA(s2, s3)), FA(FA(s4, s5), FA(s6, s7)));
  }
#pragma unroll
  for (int h = 8; h >= 1; h >>= 1)
#pragma unroll
    for (int l = 0; l < 8; l++)
      if (l < h) lane[l] = FA(lane[l], lane[l + h]);
  return lane[0];
}

static __device__ __forceinline__ float np_sumsq256(const float* __restrict__ p) {
  return FA(np_sumsq128(p), np_sumsq128(p + 128));
}

// ---------------- K1a: codebook c2 (numpy-replica f32) ----------------------
__global__ void vqp_c2(const float* __restrict__ cb, float* __restrict__ c2n) {
  const int code = blockIdx.x * 256 + threadIdx.x;
  if (code < KC) c2n[code] = np_sumsq256(cb + (size_t)code * DD);
}

// ---------------- K1b: codebook bf16 hi split, MFMA-granule layout ----------
// Tile t (16 codes) = 8KB = 512 granules of 16B. Granule gi within tile:
// kc=gi>>6, q=(gi>>4)&3, c=gi&15 holds bf16_hi(cb[t*16+c][kc*32+q*8+j]) j=0..7.
// A-frag ds_read is lane-linear: addr = kc*1024B + lane*16B (conflict-free).
__global__ void vqp_cbsplit(const float* __restrict__ cb,
                            unsigned short* __restrict__ cbs) {
  const int g  = blockIdx.x * 256 + threadIdx.x;   // 0..32767
  const int t  = g >> 9;
  const int gi = g & 511;
  const int kc = gi >> 6, q = (gi >> 4) & 3, c = gi & 15;
  const float* src = cb + (size_t)(t * 16 + c) * DD + kc * 32 + q * 8;
  unsigned int w[4];
#pragma unroll
  for (int p = 0; p < 4; p++)
    w[p] = (unsigned int)bf16h(src[p * 2]) |
           ((unsigned int)bf16h(src[p * 2 + 1]) << 16);
  *(uint4*)(cbs + (size_t)g * 8) = make_uint4(w[0], w[1], w[2], w[3]);
}

// ---------------- K2: 1-pass MFMA screen + exact-np rescore + outputs -------
// 64 rows/WG (2048 WGs), 4 waves; wave w owns rows w*16+(lane&15).
// 6 WGs/CU resident (LDS 26.6KB, VGPR<=84) so WGs de-phase: one WG's
// prologue/epilogue HBM hides under others' MFMA loop. 64 code-tiles of 16;
// per tile per kc one A-read (hi codes) + 1 MFMA. z2 in-prologue (exact np
// AVX512 tree). Selection layer guarantees np-f32 bit-exactness: candidates
// within MARG of running min; single filtered candidate -> argmin; else
// exact sequential-f32 np rescore (lex (d, code) first-min). Epilogue: one
// wave per row, fully coalesced 1KB-per-instruction gather/store.
__global__ __launch_bounds__(256, 6) void vqp_main(
    const float* __restrict__ z, const float* __restrict__ cb,
    const unsigned short* __restrict__ cbs,
    const float* __restrict__ c2n,
    float* __restrict__ out, int* __restrict__ counts,
    double* __restrict__ bss) {
  __shared__ __align__(16) unsigned short ct[2][4096];  // 16 KB code-tile dbuf
  __shared__ unsigned short ccode[64][CCAP];            //  3 KB
  __shared__ float cd[64][CCAP];                        //  6 KB
  __shared__ int ccnt[64];
  __shared__ float m1row[64];
  __shared__ float z2s[64];
  __shared__ int rowidx[64];
  __shared__ double wred[4];

  const int tid = threadIdx.x, wg = blockIdx.x;
  const int wv = tid >> 6, ln = tid & 63;
  const int rl = ln & 15;           // row within wave's 16
  const int qk = ln >> 4;           // k-octet / code-quad selector
  const int rw = wv * 16 + rl;      // row local to WG
  const int rowg = wg * 64 + rw;    // global row

  // stage tile T into buffer B: 2 glds per wave (1KB each)
#define STG(T, B) do {                                                        \
    _Pragma("unroll")                                                         \
    for (int u_ = 0; u_ < 2; u_++) {                                          \
      glds16(cbs + (size_t)(T) * 4096 + (size_t)((wv * 2 + u_) * 64 + ln) * 8,\
             &ct[B][(wv * 2 + u_) * 512]);                                    \
    }                                                                         \
  } while (0)

  STG(0, 0);

  // ---- build z hi-fragments in registers ----
  bf16x8 zH[8];
#pragma unroll
  for (int kc = 0; kc < 8; kc++) {
    const float4* p0 = (const float4*)(z + (size_t)rowg * DD + kc * 32 + qk * 8);
    const float4 a0 = p0[0], b0 = p0[1];
    zH[kc][0] = (short)bf16h(a0.x); zH[kc][1] = (short)bf16h(a0.y);
    zH[kc][2] = (short)bf16h(a0.z); zH[kc][3] = (short)bf16h(a0.w);
    zH[kc][4] = (short)bf16h(b0.x); zH[kc][5] = (short)bf16h(b0.y);
    zH[kc][6] = (short)bf16h(b0.z); zH[kc][7] = (short)bf16h(b0.w);
  }

  // ---- in-prologue z2: exact np AVX512 tree, 16-lane groups ----
  {
    const int gg = ln >> 4, l = ln & 15;
#pragma unroll 1
    for (int g4 = 0; g4 < 4; g4++) {
      const int rlcl = wv * 16 + g4 * 4 + gg;
      const float* q = z + (size_t)(wg * 64 + rlcl) * DD;
      float blk[2];
#pragma unroll
      for (int b = 0; b < 2; b++) {
        const float* qq = q + b * 128;
        const float s0 = FM(qq[l +   0], qq[l +   0]);
        const float s1 = FM(qq[l +  16], qq[l +  16]);
        const float s2 = FM(qq[l +  32], qq[l +  32]);
        const float s3 = FM(qq[l +  48], qq[l +  48]);
        const float s4 = FM(qq[l +  64], qq[l +  64]);
        const float s5 = FM(qq[l +  80], qq[l +  80]);
        const float s6 = FM(qq[l +  96], qq[l +  96]);
        const float s7 = FM(qq[l + 112], qq[l + 112]);
        float v = FA(FA(FA(s0, s1), FA(s2, s3)), FA(FA(s4, s5), FA(s6, s7)));
#pragma unroll
        for (int h = 8; h >= 1; h >>= 1) v = FA(v, __shfl_down(v, h, 16));
        blk[b] = v;
      }
      if (l == 0) z2s[rlcl] = FA(blk[0], blk[1]);
    }
  }
  if (tid < 64) ccnt[tid] = 0;
  __syncthreads();            // z2s visible (also orders ccnt init)

  const float z2v = z2s[rw];

  float m1 = INFINITY;
#pragma unroll 1
  for (int t = 0; t < 64; t++) {
    if (t < 63) {
      STG(t + 1, (t + 1) & 1);
      asm volatile("s_waitcnt vmcnt(2)" ::: "memory");  // tile-t loads done
    } else {
      asm volatile("s_waitcnt vmcnt(0)" ::: "memory");
    }
    __builtin_amdgcn_sched_barrier(0);
    __builtin_amdgcn_s_barrier();

    const unsigned short* cbuf = ct[t & 1];
    f32x4 accA = {0.f, 0.f, 0.f, 0.f};
#pragma unroll
    for (int kc = 0; kc < 8; kc++) {
      const bf16x8 aH = *(const bf16x8*)&cbuf[kc * 512 + ln * 8];
      accA = __builtin_amdgcn_mfma_f32_16x16x32_bf16(aH, zH[kc], accA, 0, 0, 0);
    }
    // fold: lane covers codes t*16 + qk*4 + r for row rl
    float dh[4];
#pragma unroll
    for (int r = 0; r < 4; r++) {
      const float c2v = c2n[t * 16 + qk * 4 + r];
      dh[r] = z2v - 2.f * accA[r] + c2v;
      m1 = fminf(m1, dh[r]);
    }
    m1 = fminf(m1, __shfl_xor(m1, 16));
    m1 = fminf(m1, __shfl_xor(m1, 32));
#pragma unroll
    for (int r = 0; r < 4; r++) {
      if (dh[r] <= m1 + MARG) {
        const int s = atomicAdd(&ccnt[rw], 1);
        if (s < CCAP) {
          ccode[rw][s] = (unsigned short)(t * 16 + qk * 4 + r);
          cd[rw][s] = dh[r];
        }
      }
    }
    __builtin_amdgcn_s_barrier();     // buffer reuse guard
  }
#undef STG

  if (qk == 0) m1row[rw] = m1;
  __syncthreads();

  // ---- finalize: filter candidates; exact np rescore where needed ----
  if (tid < 64) {
    const int row = wg * 64 + tid;
    const float mf = m1row[tid] + MARG;
    const int nc = ccnt[tid];
    int best;
    if (nc > CCAP) {             // overflow (P~0): full exact np scan
      const float* zr = z + (size_t)row * DD;
      const float z2r = z2s[tid];
      float db = INFINITY; best = 0;
      for (int c = 0; c < KC; c++) {
        const float* cr = cb + (size_t)c * DD;
        float dot = 0.f;
#pragma unroll 8
        for (int k = 0; k < DD; k++) dot = __fmaf_rn(zr[k], cr[k], dot);
        const float t1 = 2.0f * dot;
        const float d = FA(FA(z2r, -t1), c2n[c]);
        if (d < db) { db = d; best = c; }          // ascending c: first-min
      }
    } else {
      int kept = 0, kcode = 0;
      for (int s = 0; s < nc; s++)
        if (cd[tid][s] <= mf) { kept++; kcode = ccode[tid][s]; }
      if (kept == 1) best = kcode;
      else {
        const float* zr = z + (size_t)row * DD;
        const float z2r = z2s[tid];
        float db = INFINITY; int bi = 0x7FFFFFFF;
        for (int s = 0; s < nc; s++) {
          if (cd[tid][s] > mf) continue;
          const int c = ccode[tid][s];
          const float* cr = cb + (size_t)c * DD;
          float dot = 0.f;
#pragma unroll 8
          for (int k = 0; k < DD; k++) dot = __fmaf_rn(zr[k], cr[k], dot);
          const float t1 = 2.0f * dot;
          const float d = FA(FA(z2r, -t1), c2n[c]);   // exact np-f32 d
          if (d < db || (d == db && c < bi)) { db = d; bi = c; }
        }
        best = bi;
      }
    }
    rowidx[tid] = best;
    atomicAdd(&counts[best], 1);
    out[IDX_OFF + row] = (float)best;
  }
  __syncthreads();

  // ---- gather + zq_st / residual: one wave per row, fully coalesced ----
  float ss = 0.f;
#pragma unroll 1
  for (int g = 0; g < 16; g++) {
    const int rlcl = wv * 16 + g;
    const int id   = rowidx[rlcl];
    const size_t zrow = (size_t)(wg * 64 + rlcl) * DD;
    const float4 r4 = ((const float4*)(z  + zrow))[ln];
    const float4 q4 = ((const float4*)(cb + (size_t)id * DD))[ln];
    float4 stv, rsv; float dq;
    stv.x = r4.x + (q4.x - r4.x); rsv.x = r4.x - q4.x; dq = q4.x - r4.x; ss = fmaf(dq, dq, ss);
    stv.y = r4.y + (q4.y - r4.y); rsv.y = r4.y - q4.y; dq = q4.y - r4.y; ss = fmaf(dq, dq, ss);
    stv.z = r4.z + (q4.z - r4.z); rsv.z = r4.z - q4.z; dq = q4.z - r4.z; ss = fmaf(dq, dq, ss);
    stv.w = r4.w + (q4.w - r4.w); rsv.w = r4.w - q4.w; dq = q4.w - r4.w; ss = fmaf(dq, dq, ss);
    ((float4*)(out + ZQ_OFF  + zrow))[ln] = stv;
    ((float4*)(out + RES_OFF + zrow))[ln] = rsv;
  }
  double dss = (double)ss;
  for (int o = 32; o; o >>= 1) dss += __shfl_down(dss, o, 64);
  if (ln == 0) wred[wv] = dss;
  __syncthreads();
  if (tid == 0) bss[wg] = wred[0] + wred[1] + wred[2] + wred[3];
}

// ---------------- K3: scalars (loss, perplexity) ----------------------------
__global__ void vqp_final(const int* __restrict__ counts,
                          const double* __restrict__ bss,
                          float* __restrict__ out) {
  __shared__ double red[256];
  const int t = threadIdx.x;
  double s = 0.0;
  for (int i = t; i < 2048; i += 256) s += bss[i];
  red[t] = s; __syncthreads();
  for (int s2 = 128; s2 > 0; s2 >>= 1) { if (t < s2) red[t] += red[t + s2]; __syncthreads(); }
  const double ssq = red[0];
  __syncthreads();
  double h = 0.0;
  for (int c = t; c < 1024; c += 256) {
    double p = (double)counts[c] / 131072.0;
    h += p * log(p + 1e-10);
  }
  red[t] = h; __syncthreads();
  for (int s2 = 128; s2 > 0; s2 >>= 1) { if (t < s2) red[t] += red[t + s2]; __syncthreads(); }
  if (t == 0) {
    out[LOSS_OFF] = (float)(0.25 * ssq / 33554432.0);
    out[PERP_OFF] = (float)exp(-red[0]);
  }
}

extern "C" void kernel_launch(void* const* d_in, const int* in_sizes, int n_in,
                              void* d_out, int out_size, void* d_ws, size_t ws_size,
                              hipStream_t stream) {
  // Bind inputs by SIZE: z has 33,554,432 elems, codebook 262,144.
  const float* z;
  const float* cb;
  if (in_sizes[0] == NR * DD) { z = (const float*)d_in[0]; cb = (const float*)d_in[1]; }
  else                        { cb = (const float*)d_in[0]; z = (const float*)d_in[1]; }

  float* out = (float*)d_out;
  char* ws = (char*)d_ws;
  int*            counts = (int*)(ws + WS_CNT);
  float*          c2n    = (float*)(ws + WS_C2N);
  double*         bssp   = (double*)(ws + WS_BSS);
  unsigned short* cbs    = (unsigned short*)(ws + WS_CBS);

  hipMemsetAsync(counts, 0, 4096, stream);
  vqp_c2<<<4, 256, 0, stream>>>(cb, c2n);
  vqp_cbsplit<<<128, 256, 0, stream>>>(cb, cbs);
  vqp_main<<<NR / 64, 256, 0, stream>>>(z, cb, cbs, c2n, out, counts, bssp);
  vqp_final<<<1, 256, 0, stream>>>(counts, bssp, out);
}

// Round 16
// 320.636 us; speedup vs baseline: 1.0752x; 1.0752x over previous
//
#include <hip/hip_runtime.h>
#include <math.h>

#define NR 131072
#define KC 1024
#define DD 256

// d_out element offsets (float32 elements)
#define ZQ_OFF  0
#define RES_OFF 33554432
#define IDX_OFF 67108864
#define LOSS_OFF 67239936
#define PERP_OFF 67239937

// ws byte offsets (total ~536 KB)
#define WS_CNT 0          // int[1024]
#define WS_C2N 4096       // float[1024]
#define WS_BSS 8192       // double[1024]
#define WS_CBS 16384      // ushort cbs hi-only: 64 tiles x 8KB = 512KB

#define MARG 5e-4f
#define CCAP 24

#define FM(x,y) __fmul_rn((x),(y))
#define FA(x,y) __fadd_rn((x),(y))

typedef __attribute__((ext_vector_type(8))) short bf16x8;
typedef __attribute__((ext_vector_type(4))) float f32x4;

static __device__ __forceinline__ unsigned short bf16h(float f) {
  unsigned int u = __float_as_uint(f);
  u += 0x7FFFu + ((u >> 16) & 1u);
  return (unsigned short)(u >> 16);
}

// ---- numpy f32 pairwise sum-of-squares, one 128-block (AVX512 tree) --------
static __device__ __forceinline__ float np_sumsq128(const float* __restrict__ q) {
  float lane[16];
#pragma unroll
  for (int l = 0; l < 16; l++) {
    float s0 = FM(q[l +   0], q[l +   0]);
    float s1 = FM(q[l +  16], q[l +  16]);
    float s2 = FM(q[l +  32], q[l +  32]);
    float s3 = FM(q[l +  48], q[l +  48]);
    float s4 = FM(q[l +  64], q[l +  64]);
    float s5 = FM(q[l +  80], q[l +  80]);
    float s6 = FM(q[l +  96], q[l +  96]);
    float s7 = FM(q[l + 112], q[l + 112]);
    lane[l] = FA(FA(FA(s0, s1), FA(s2, s3)), FA(FA(s4, s5), FA(s6, s7)));
  }
#pragma unroll
  for (int h = 8; h >= 1; h >>= 1)
#pragma unroll
    for (int l = 0; l < 8; l++)
      if (l < h) lane[l] = FA(lane[l], lane[l + h]);
  return lane[0];
}

static __device__ __forceinline__ float np_sumsq256(const float* __restrict__ p) {
  return FA(np_sumsq128(p), np_sumsq128(p + 128));
}

// ---------------- K1a: codebook c2 (numpy-replica f32) ----------------------
__global__ void vqq_c2(const float* __restrict__ cb, float* __restrict__ c2n) {
  const int code = blockIdx.x * 256 + threadIdx.x;
  if (code < KC) c2n[code] = np_sumsq256(cb + (size_t)code * DD);
}

// ---------------- K1b: codebook bf16 hi split, MFMA-granule layout ----------
// Tile t (16 codes) = 8KB = 512 granules of 16B. Granule gi within tile:
// kc=gi>>6, q=(gi>>4)&3, c=gi&15 holds bf16_hi(cb[t*16+c][kc*32+q*8+j]) j=0..7.
// A-frag load is lane-linear: byte addr = t*8192 + kc*1024 + lane*16, so one
// global_load_dwordx4 per (tile,kc) fetches a contiguous 1KB -> pure L2 stream.
__global__ void vqq_cbsplit(const float* __restrict__ cb,
                            unsigned short* __restrict__ cbs) {
  const int g  = blockIdx.x * 256 + threadIdx.x;   // 0..32767
  const int t  = g >> 9;
  const int gi = g & 511;
  const int kc = gi >> 6, q = (gi >> 4) & 3, c = gi & 15;
  const float* src = cb + (size_t)(t * 16 + c) * DD + kc * 32 + q * 8;
  unsigned int w[4];
#pragma unroll
  for (int p = 0; p < 4; p++)
    w[p] = (unsigned int)bf16h(src[p * 2]) |
           ((unsigned int)bf16h(src[p * 2 + 1]) << 16);
  *(uint4*)(cbs + (size_t)g * 8) = make_uint4(w[0], w[1], w[2], w[3]);
}

// ---------------- K2: barrier-free MFMA screen + exact-np rescore -----------
// 128 rows/WG (1024 WGs), 4 waves; wave w owns rows w*32 + {0..31} as two
// 16-row groups. A-fragments (hi codes) loaded DIRECTLY global->register from
// L2-resident cbs — no LDS staging, no barriers in the 64-tile loop; waves
// run free and the compiler pipelines the 8 independent loads per tile
// (unroll 2 overlaps tile t+1 loads with tile t MFMAs). Selection layer
// guarantees np-f32 bit-exactness: candidates within MARG of running min;
// single filtered candidate -> argmin; else exact sequential-f32 np rescore
// (lex (d, code) first-min). Finalize distributed across all 4 waves.
// Epilogue: one wave per row, fully coalesced 1KB-per-instruction.
__global__ __launch_bounds__(256, 4) void vqq_main(
    const float* __restrict__ z, const float* __restrict__ cb,
    const unsigned short* __restrict__ cbs,
    const float* __restrict__ c2n,
    float* __restrict__ out, int* __restrict__ counts,
    double* __restrict__ bss) {
  __shared__ unsigned short ccode[128][CCAP];           //  6 KB
  __shared__ float cd[128][CCAP];                       // 12 KB
  __shared__ int ccnt[128];
  __shared__ float m1row[128];
  __shared__ float z2s[128];
  __shared__ int rowidx[128];
  __shared__ __align__(16) float c2l[1024];             //  4 KB
  __shared__ double wred[4];

  const int tid = threadIdx.x, wg = blockIdx.x;
  const int wv = tid >> 6, ln = tid & 63;
  const int rl = ln & 15;           // row within group
  const int qk = ln >> 4;           // k-octet / code-quad selector
  const int rowg0 = wg * 128 + wv * 32 + rl;      // group-0 global row

  // ---- c2 into LDS (broadcast reads later) ----
  ((float4*)c2l)[tid] = ((const float4*)c2n)[tid];

  // ---- build z hi-fragments in registers for both row-groups ----
  bf16x8 zH0[8], zH1[8];
#pragma unroll
  for (int kc = 0; kc < 8; kc++) {
    const float4* p0 = (const float4*)(z + (size_t)rowg0 * DD + kc * 32 + qk * 8);
    const float4* p1 = (const float4*)(z + (size_t)(rowg0 + 16) * DD + kc * 32 + qk * 8);
    const float4 a0 = p0[0], b0 = p0[1];
    const float4 a1 = p1[0], b1 = p1[1];
    zH0[kc][0] = (short)bf16h(a0.x); zH0[kc][1] = (short)bf16h(a0.y);
    zH0[kc][2] = (short)bf16h(a0.z); zH0[kc][3] = (short)bf16h(a0.w);
    zH0[kc][4] = (short)bf16h(b0.x); zH0[kc][5] = (short)bf16h(b0.y);
    zH0[kc][6] = (short)bf16h(b0.z); zH0[kc][7] = (short)bf16h(b0.w);
    zH1[kc][0] = (short)bf16h(a1.x); zH1[kc][1] = (short)bf16h(a1.y);
    zH1[kc][2] = (short)bf16h(a1.z); zH1[kc][3] = (short)bf16h(a1.w);
    zH1[kc][4] = (short)bf16h(b1.x); zH1[kc][5] = (short)bf16h(b1.y);
    zH1[kc][6] = (short)bf16h(b1.z); zH1[kc][7] = (short)bf16h(b1.w);
  }

  // ---- in-prologue z2: exact np AVX512 tree, 16-lane groups ----
  {
    const int gg = ln >> 4, l = ln & 15;
#pragma unroll 1
    for (int g4 = 0; g4 < 8; g4++) {
      const int rlcl = wv * 32 + g4 * 4 + gg;
      const float* q = z + (size_t)(wg * 128 + rlcl) * DD;
      float blk[2];
#pragma unroll
      for (int b = 0; b < 2; b++) {
        const float* qq = q + b * 128;
        const float s0 = FM(qq[l +   0], qq[l +   0]);
        const float s1 = FM(qq[l +  16], qq[l +  16]);
        const float s2 = FM(qq[l +  32], qq[l +  32]);
        const float s3 = FM(qq[l +  48], qq[l +  48]);
        const float s4 = FM(qq[l +  64], qq[l +  64]);
        const float s5 = FM(qq[l +  80], qq[l +  80]);
        const float s6 = FM(qq[l +  96], qq[l +  96]);
        const float s7 = FM(qq[l + 112], qq[l + 112]);
        float v = FA(FA(FA(s0, s1), FA(s2, s3)), FA(FA(s4, s5), FA(s6, s7)));
#pragma unroll
        for (int h = 8; h >= 1; h >>= 1) v = FA(v, __shfl_down(v, h, 16));
        blk[b] = v;
      }
      if (l == 0) z2s[rlcl] = FA(blk[0], blk[1]);
    }
  }
  if (tid < 128) ccnt[tid] = 0;
  __syncthreads();            // z2s/c2l visible, ccnt init ordered

  const float z2v0 = z2s[wv * 32 + rl];
  const float z2v1 = z2s[wv * 32 + rl + 16];
  const int rw0 = wv * 32 + rl;

  float m10 = INFINITY, m11 = INFINITY;
#pragma unroll 2
  for (int t = 0; t < 64; t++) {
    // direct global->register A-fragments (L2-resident cbs, coalesced 1KB/load)
    bf16x8 aH[8];
#pragma unroll
    for (int kc = 0; kc < 8; kc++)
      aH[kc] = *(const bf16x8*)(cbs + (size_t)t * 4096 + kc * 512 + ln * 8);

    f32x4 accA = {0.f, 0.f, 0.f, 0.f}, accB = accA;
#pragma unroll
    for (int kc = 0; kc < 8; kc++) {
      accA = __builtin_amdgcn_mfma_f32_16x16x32_bf16(aH[kc], zH0[kc], accA, 0, 0, 0);
      accB = __builtin_amdgcn_mfma_f32_16x16x32_bf16(aH[kc], zH1[kc], accB, 0, 0, 0);
    }
    // fold: lane covers codes t*16 + qk*4 + r, rows (group0, group1)
    const float4 c2v4 = *(const float4*)&c2l[t * 16 + qk * 4];
    float dh0[4], dh1[4];
#pragma unroll
    for (int r = 0; r < 4; r++) {
      const float c2v = r == 0 ? c2v4.x : r == 1 ? c2v4.y : r == 2 ? c2v4.z : c2v4.w;
      dh0[r] = z2v0 - 2.f * accA[r] + c2v;
      dh1[r] = z2v1 - 2.f * accB[r] + c2v;
      m10 = fminf(m10, dh0[r]);
      m11 = fminf(m11, dh1[r]);
    }
    m10 = fminf(m10, __shfl_xor(m10, 16));
    m10 = fminf(m10, __shfl_xor(m10, 32));
    m11 = fminf(m11, __shfl_xor(m11, 16));
    m11 = fminf(m11, __shfl_xor(m11, 32));
#pragma unroll
    for (int r = 0; r < 4; r++) {
      if (dh0[r] <= m10 + MARG) {
        const int s = atomicAdd(&ccnt[rw0], 1);
        if (s < CCAP) {
          ccode[rw0][s] = (unsigned short)(t * 16 + qk * 4 + r);
          cd[rw0][s] = dh0[r];
        }
      }
      if (dh1[r] <= m11 + MARG) {
        const int s = atomicAdd(&ccnt[rw0 + 16], 1);
        if (s < CCAP) {
          ccode[rw0 + 16][s] = (unsigned short)(t * 16 + qk * 4 + r);
          cd[rw0 + 16][s] = dh1[r];
        }
      }
    }
  }

  if (qk == 0) { m1row[rw0] = m10; m1row[rw0 + 16] = m11; }
  __syncthreads();

  // ---- finalize (distributed: wave wv, lanes 0..31 -> rows wv*32+ln) ----
  if (ln < 32) {
    const int rwl = wv * 32 + ln;
    const int row = wg * 128 + rwl;
    const float mf = m1row[rwl] + MARG;
    const int nc = ccnt[rwl];
    int best;
    if (nc > CCAP) {             // overflow (P~0): full exact np scan
      const float* zr = z + (size_t)row * DD;
      const float z2r = z2s[rwl];
      float db = INFINITY; best = 0;
      for (int c = 0; c < KC; c++) {
        const float* cr = cb + (size_t)c * DD;
        float dot = 0.f;
#pragma unroll 8
        for (int k = 0; k < DD; k++) dot = __fmaf_rn(zr[k], cr[k], dot);
        const float t1 = 2.0f * dot;
        const float d = FA(FA(z2r, -t1), c2l[c]);
        if (d < db) { db = d; best = c; }          // ascending c: first-min
      }
    } else {
      int kept = 0, kcode = 0;
      for (int s = 0; s < nc; s++)
        if (cd[rwl][s] <= mf) { kept++; kcode = ccode[rwl][s]; }
      if (kept == 1) best = kcode;
      else {
        const float* zr = z + (size_t)row * DD;
        const float z2r = z2s[rwl];
        float db = INFINITY; int bi = 0x7FFFFFFF;
        for (int s = 0; s < nc; s++) {
          if (cd[rwl][s] > mf) continue;
          const int c = ccode[rwl][s];
          const float* cr = cb + (size_t)c * DD;
          float dot = 0.f;
#pragma unroll 8
          for (int k = 0; k < DD; k++) dot = __fmaf_rn(zr[k], cr[k], dot);
          const float t1 = 2.0f * dot;
          const float d = FA(FA(z2r, -t1), c2l[c]);   // exact np-f32 d
          if (d < db || (d == db && c < bi)) { db = d; bi = c; }
        }
        best = bi;
      }
    }
    rowidx[rwl] = best;
    atomicAdd(&counts[best], 1);
    out[IDX_OFF + row] = (float)best;
  }
  __syncthreads();

  // ---- gather + zq_st / residual: one wave per row, fully coalesced ----
  float ss = 0.f;
#pragma unroll 1
  for (int g = 0; g < 32; g++) {
    const int rlcl = wv * 32 + g;
    const int id   = rowidx[rlcl];
    const size_t zrow = (size_t)(wg * 128 + rlcl) * DD;
    const float4 r4 = ((const float4*)(z  + zrow))[ln];
    const float4 q4 = ((const float4*)(cb + (size_t)id * DD))[ln];
    float4 stv, rsv; float dq;
    stv.x = r4.x + (q4.x - r4.x); rsv.x = r4.x - q4.x; dq = q4.x - r4.x; ss = fmaf(dq, dq, ss);
    stv.y = r4.y + (q4.y - r4.y); rsv.y = r4.y - q4.y; dq = q4.y - r4.y; ss = fmaf(dq, dq, ss);
    stv.z = r4.z + (q4.z - r4.z); rsv.z = r4.z - q4.z; dq = q4.z - r4.z; ss = fmaf(dq, dq, ss);
    stv.w = r4.w + (q4.w - r4.w); rsv.w = r4.w - q4.w; dq = q4.w - r4.w; ss = fmaf(dq, dq, ss);
    ((float4*)(out + ZQ_OFF  + zrow))[ln] = stv;
    ((float4*)(out + RES_OFF + zrow))[ln] = rsv;
  }
  double dss = (double)ss;
  for (int o = 32; o; o >>= 1) dss += __shfl_down(dss, o, 64);
  if (ln == 0) wred[wv] = dss;
  __syncthreads();
  if (tid == 0) bss[wg] = wred[0] + wred[1] + wred[2] + wred[3];
}

// ---------------- K3: scalars (loss, perplexity) ----------------------------
__global__ void vqq_final(const int* __restrict__ counts,
                          const double* __restrict__ bss,
                          float* __restrict__ out) {
  __shared__ double red[256];
  const int t = threadIdx.x;
  double s = 0.0;
  for (int i = t; i < 1024; i += 256) s += bss[i];
  red[t] = s; __syncthreads();
  for (int s2 = 128; s2 > 0; s2 >>= 1) { if (t < s2) red[t] += red[t + s2]; __syncthreads(); }
  const double ssq = red[0];
  __syncthreads();
  double h = 0.0;
  for (int c = t; c < 1024; c += 256) {
    double p = (double)counts[c] / 131072.0;
    h += p * log(p + 1e-10);
  }
  red[t] = h; __syncthreads();
  for (int s2 = 128; s2 > 0; s2 >>= 1) { if (t < s2) red[t] += red[t + s2]; __syncthreads(); }
  if (t == 0) {
    out[LOSS_OFF] = (float)(0.25 * ssq / 33554432.0);
    out[PERP_OFF] = (float)exp(-red[0]);
  }
}

extern "C" void kernel_launch(void* const* d_in, const int* in_sizes, int n_in,
                              void* d_out, int out_size, void* d_ws, size_t ws_size,
                              hipStream_t stream) {
  // Bind inputs by SIZE: z has 33,554,432 elems, codebook 262,144.
  const float* z;
  const float* cb;
  if (in_sizes[0] == NR * DD) { z = (const float*)d_in[0]; cb = (const float*)d_in[1]; }
  else                        { cb = (const float*)d_in[0]; z = (const float*)d_in[1]; }

  float* out = (float*)d_out;
  char* ws = (char*)d_ws;
  int*            counts = (int*)(ws + WS_CNT);
  float*          c2n    = (float*)(ws + WS_C2N);
  double*         bssp   = (double*)(ws + WS_BSS);
  unsigned short* cbs    = (unsigned short*)(ws + WS_CBS);

  hipMemsetAsync(counts, 0, 4096, stream);
  vqq_c2<<<4, 256, 0, stream>>>(cb, c2n);
  vqq_cbsplit<<<128, 256, 0, stream>>>(cb, cbs);
  vqq_main<<<NR / 128, 256, 0, stream>>>(z, cb, cbs, c2n, out, counts, bssp);
  vqq_final<<<1, 256, 0, stream>>>(counts, bssp, out);
}

// Round 17
// 310.360 us; speedup vs baseline: 1.1108x; 1.0331x over previous
//
#include <hip/hip_runtime.h>
#include <math.h>

#define NR 131072
#define KC 1024
#define DD 256

// d_out element offsets (float32 elements)
#define ZQ_OFF  0
#define RES_OFF 33554432
#define IDX_OFF 67108864
#define LOSS_OFF 67239936
#define PERP_OFF 67239937

// ws byte offsets (total ~536 KB)
#define WS_CNT 0          // int[1024]
#define WS_C2N 4096       // float[1024]
#define WS_BSS 8192       // double[1024]
#define WS_CBS 16384      // ushort cbs hi-only: 64 tiles x 8KB = 512KB

#define MARG 5e-4f
#define CCAP 24

#define FM(x,y) __fmul_rn((x),(y))
#define FA(x,y) __fadd_rn((x),(y))

typedef __attribute__((ext_vector_type(8))) short bf16x8;
typedef __attribute__((ext_vector_type(4))) float f32x4;

static __device__ __forceinline__ unsigned short bf16h(float f) {
  unsigned int u = __float_as_uint(f);
  u += 0x7FFFu + ((u >> 16) & 1u);
  return (unsigned short)(u >> 16);
}

// ---- numpy f32 pairwise sum-of-squares, one 128-block (AVX512 tree) --------
static __device__ __forceinline__ float np_sumsq128(const float* __restrict__ q) {
  float lane[16];
#pragma unroll
  for (int l = 0; l < 16; l++) {
    float s0 = FM(q[l +   0], q[l +   0]);
    float s1 = FM(q[l +  16], q[l +  16]);
    float s2 = FM(q[l +  32], q[l +  32]);
    float s3 = FM(q[l +  48], q[l +  48]);
    float s4 = FM(q[l +  64], q[l +  64]);
    float s5 = FM(q[l +  80], q[l +  80]);
    float s6 = FM(q[l +  96], q[l +  96]);
    float s7 = FM(q[l + 112], q[l + 112]);
    lane[l] = FA(FA(FA(s0, s1), FA(s2, s3)), FA(FA(s4, s5), FA(s6, s7)));
  }
#pragma unroll
  for (int h = 8; h >= 1; h >>= 1)
#pragma unroll
    for (int l = 0; l < 8; l++)
      if (l < h) lane[l] = FA(lane[l], lane[l + h]);
  return lane[0];
}

static __device__ __forceinline__ float np_sumsq256(const float* __restrict__ p) {
  return FA(np_sumsq128(p), np_sumsq128(p + 128));
}

// ---------------- K1a: codebook c2 (numpy-replica f32) ----------------------
__global__ void vqr_c2(const float* __restrict__ cb, float* __restrict__ c2n) {
  const int code = blockIdx.x * 256 + threadIdx.x;
  if (code < KC) c2n[code] = np_sumsq256(cb + (size_t)code * DD);
}

// ---------------- K1b: codebook bf16 hi split, MFMA-granule layout ----------
// Tile t (16 codes) = 8KB = 512 granules of 16B. Granule gi within tile:
// kc=gi>>6, q=(gi>>4)&3, c=gi&15 holds bf16_hi(cb[t*16+c][kc*32+q*8+j]) j=0..7.
// A-frag load is lane-linear: byte addr = t*8192 + kc*1024 + lane*16, so one
// global_load_dwordx4 per (tile,kc) fetches a contiguous 1KB -> pure L2 stream.
__global__ void vqr_cbsplit(const float* __restrict__ cb,
                            unsigned short* __restrict__ cbs) {
  const int g  = blockIdx.x * 256 + threadIdx.x;   // 0..32767
  const int t  = g >> 9;
  const int gi = g & 511;
  const int kc = gi >> 6, q = (gi >> 4) & 3, c = gi & 15;
  const float* src = cb + (size_t)(t * 16 + c) * DD + kc * 32 + q * 8;
  unsigned int w[4];
#pragma unroll
  for (int p = 0; p < 4; p++)
    w[p] = (unsigned int)bf16h(src[p * 2]) |
           ((unsigned int)bf16h(src[p * 2 + 1]) << 16);
  *(uint4*)(cbs + (size_t)g * 8) = make_uint4(w[0], w[1], w[2], w[3]);
}

// ---------------- K2: barrier-free MFMA screen + exact-np rescore -----------
// As round 16 (proven): 128 rows/WG (1024 WGs), 4 waves, direct
// global->register A-fragments from L2-resident cbs, no main-loop barriers.
// THIS ROUND: epilogue batches 8 rows -> 16 independent loads in flight per
// wave (MLP fix; epilogue was latency-bound at ~350 GB/s read rate).
__global__ __launch_bounds__(256, 4) void vqr_main(
    const float* __restrict__ z, const float* __restrict__ cb,
    const unsigned short* __restrict__ cbs,
    const float* __restrict__ c2n,
    float* __restrict__ out, int* __restrict__ counts,
    double* __restrict__ bss) {
  __shared__ unsigned short ccode[128][CCAP];           //  6 KB
  __shared__ float cd[128][CCAP];                       // 12 KB
  __shared__ int ccnt[128];
  __shared__ float m1row[128];
  __shared__ float z2s[128];
  __shared__ int rowidx[128];
  __shared__ __align__(16) float c2l[1024];             //  4 KB
  __shared__ double wred[4];

  const int tid = threadIdx.x, wg = blockIdx.x;
  const int wv = tid >> 6, ln = tid & 63;
  const int rl = ln & 15;           // row within group
  const int qk = ln >> 4;           // k-octet / code-quad selector
  const int rowg0 = wg * 128 + wv * 32 + rl;      // group-0 global row

  // ---- c2 into LDS (broadcast reads later) ----
  ((float4*)c2l)[tid] = ((const float4*)c2n)[tid];

  // ---- build z hi-fragments in registers for both row-groups ----
  bf16x8 zH0[8], zH1[8];
#pragma unroll
  for (int kc = 0; kc < 8; kc++) {
    const float4* p0 = (const float4*)(z + (size_t)rowg0 * DD + kc * 32 + qk * 8);
    const float4* p1 = (const float4*)(z + (size_t)(rowg0 + 16) * DD + kc * 32 + qk * 8);
    const float4 a0 = p0[0], b0 = p0[1];
    const float4 a1 = p1[0], b1 = p1[1];
    zH0[kc][0] = (short)bf16h(a0.x); zH0[kc][1] = (short)bf16h(a0.y);
    zH0[kc][2] = (short)bf16h(a0.z); zH0[kc][3] = (short)bf16h(a0.w);
    zH0[kc][4] = (short)bf16h(b0.x); zH0[kc][5] = (short)bf16h(b0.y);
    zH0[kc][6] = (short)bf16h(b0.z); zH0[kc][7] = (short)bf16h(b0.w);
    zH1[kc][0] = (short)bf16h(a1.x); zH1[kc][1] = (short)bf16h(a1.y);
    zH1[kc][2] = (short)bf16h(a1.z); zH1[kc][3] = (short)bf16h(a1.w);
    zH1[kc][4] = (short)bf16h(b1.x); zH1[kc][5] = (short)bf16h(b1.y);
    zH1[kc][6] = (short)bf16h(b1.z); zH1[kc][7] = (short)bf16h(b1.w);
  }

  // ---- in-prologue z2: exact np AVX512 tree, 16-lane groups ----
  {
    const int gg = ln >> 4, l = ln & 15;
#pragma unroll 1
    for (int g4 = 0; g4 < 8; g4++) {
      const int rlcl = wv * 32 + g4 * 4 + gg;
      const float* q = z + (size_t)(wg * 128 + rlcl) * DD;
      float blk[2];
#pragma unroll
      for (int b = 0; b < 2; b++) {
        const float* qq = q + b * 128;
        const float s0 = FM(qq[l +   0], qq[l +   0]);
        const float s1 = FM(qq[l +  16], qq[l +  16]);
        const float s2 = FM(qq[l +  32], qq[l +  32]);
        const float s3 = FM(qq[l +  48], qq[l +  48]);
        const float s4 = FM(qq[l +  64], qq[l +  64]);
        const float s5 = FM(qq[l +  80], qq[l +  80]);
        const float s6 = FM(qq[l +  96], qq[l +  96]);
        const float s7 = FM(qq[l + 112], qq[l + 112]);
        float v = FA(FA(FA(s0, s1), FA(s2, s3)), FA(FA(s4, s5), FA(s6, s7)));
#pragma unroll
        for (int h = 8; h >= 1; h >>= 1) v = FA(v, __shfl_down(v, h, 16));
        blk[b] = v;
      }
      if (l == 0) z2s[rlcl] = FA(blk[0], blk[1]);
    }
  }
  if (tid < 128) ccnt[tid] = 0;
  __syncthreads();            // z2s/c2l visible, ccnt init ordered

  const float z2v0 = z2s[wv * 32 + rl];
  const float z2v1 = z2s[wv * 32 + rl + 16];
  const int rw0 = wv * 32 + rl;

  float m10 = INFINITY, m11 = INFINITY;
#pragma unroll 2
  for (int t = 0; t < 64; t++) {
    // direct global->register A-fragments (L2-resident cbs, coalesced 1KB/load)
    bf16x8 aH[8];
#pragma unroll
    for (int kc = 0; kc < 8; kc++)
      aH[kc] = *(const bf16x8*)(cbs + (size_t)t * 4096 + kc * 512 + ln * 8);

    f32x4 accA = {0.f, 0.f, 0.f, 0.f}, accB = accA;
#pragma unroll
    for (int kc = 0; kc < 8; kc++) {
      accA = __builtin_amdgcn_mfma_f32_16x16x32_bf16(aH[kc], zH0[kc], accA, 0, 0, 0);
      accB = __builtin_amdgcn_mfma_f32_16x16x32_bf16(aH[kc], zH1[kc], accB, 0, 0, 0);
    }
    // fold: lane covers codes t*16 + qk*4 + r, rows (group0, group1)
    const float4 c2v4 = *(const float4*)&c2l[t * 16 + qk * 4];
    float dh0[4], dh1[4];
#pragma unroll
    for (int r = 0; r < 4; r++) {
      const float c2v = r == 0 ? c2v4.x : r == 1 ? c2v4.y : r == 2 ? c2v4.z : c2v4.w;
      dh0[r] = z2v0 - 2.f * accA[r] + c2v;
      dh1[r] = z2v1 - 2.f * accB[r] + c2v;
      m10 = fminf(m10, dh0[r]);
      m11 = fminf(m11, dh1[r]);
    }
    m10 = fminf(m10, __shfl_xor(m10, 16));
    m10 = fminf(m10, __shfl_xor(m10, 32));
    m11 = fminf(m11, __shfl_xor(m11, 16));
    m11 = fminf(m11, __shfl_xor(m11, 32));
#pragma unroll
    for (int r = 0; r < 4; r++) {
      if (dh0[r] <= m10 + MARG) {
        const int s = atomicAdd(&ccnt[rw0], 1);
        if (s < CCAP) {
          ccode[rw0][s] = (unsigned short)(t * 16 + qk * 4 + r);
          cd[rw0][s] = dh0[r];
        }
      }
      if (dh1[r] <= m11 + MARG) {
        const int s = atomicAdd(&ccnt[rw0 + 16], 1);
        if (s < CCAP) {
          ccode[rw0 + 16][s] = (unsigned short)(t * 16 + qk * 4 + r);
          cd[rw0 + 16][s] = dh1[r];
        }
      }
    }
  }

  if (qk == 0) { m1row[rw0] = m10; m1row[rw0 + 16] = m11; }
  __syncthreads();

  // ---- finalize (distributed: wave wv, lanes 0..31 -> rows wv*32+ln) ----
  if (ln < 32) {
    const int rwl = wv * 32 + ln;
    const int row = wg * 128 + rwl;
    const float mf = m1row[rwl] + MARG;
    const int nc = ccnt[rwl];
    int best;
    if (nc > CCAP) {             // overflow (P~0): full exact np scan
      const float* zr = z + (size_t)row * DD;
      const float z2r = z2s[rwl];
      float db = INFINITY; best = 0;
      for (int c = 0; c < KC; c++) {
        const float* cr = cb + (size_t)c * DD;
        float dot = 0.f;
#pragma unroll 8
        for (int k = 0; k < DD; k++) dot = __fmaf_rn(zr[k], cr[k], dot);
        const float t1 = 2.0f * dot;
        const float d = FA(FA(z2r, -t1), c2l[c]);
        if (d < db) { db = d; best = c; }          // ascending c: first-min
      }
    } else {
      int kept = 0, kcode = 0;
      for (int s = 0; s < nc; s++)
        if (cd[rwl][s] <= mf) { kept++; kcode = ccode[rwl][s]; }
      if (kept == 1) best = kcode;
      else {
        const float* zr = z + (size_t)row * DD;
        const float z2r = z2s[rwl];
        float db = INFINITY; int bi = 0x7FFFFFFF;
        for (int s = 0; s < nc; s++) {
          if (cd[rwl][s] > mf) continue;
          const int c = ccode[rwl][s];
          const float* cr = cb + (size_t)c * DD;
          float dot = 0.f;
#pragma unroll 8
          for (int k = 0; k < DD; k++) dot = __fmaf_rn(zr[k], cr[k], dot);
          const float t1 = 2.0f * dot;
          const float d = FA(FA(z2r, -t1), c2l[c]);   // exact np-f32 d
          if (d < db || (d == db && c < bi)) { db = d; bi = c; }
        }
        best = bi;
      }
    }
    rowidx[rwl] = best;
    atomicAdd(&counts[best], 1);
    out[IDX_OFF + row] = (float)best;
  }
  __syncthreads();

  // ---- gather + zq_st / residual: one wave per row, 8-row batches ----
  // 16 independent loads issued per batch before any consume -> MLP ~16/wave.
  float ss = 0.f;
#pragma unroll 1
  for (int g = 0; g < 32; g += 8) {
    float4 r4b[8], q4b[8];
#pragma unroll
    for (int u = 0; u < 8; u++) {
      const int rlcl = wv * 32 + g + u;
      const size_t zrow = (size_t)(wg * 128 + rlcl) * DD;
      r4b[u] = ((const float4*)(z + zrow))[ln];
      q4b[u] = ((const float4*)(cb + (size_t)rowidx[rlcl] * DD))[ln];
    }
#pragma unroll
    for (int u = 0; u < 8; u++) {
      const int rlcl = wv * 32 + g + u;
      const size_t zrow = (size_t)(wg * 128 + rlcl) * DD;
      const float4 r4 = r4b[u];
      const float4 q4 = q4b[u];
      float4 stv, rsv; float dq;
      stv.x = r4.x + (q4.x - r4.x); rsv.x = r4.x - q4.x; dq = q4.x - r4.x; ss = fmaf(dq, dq, ss);
      stv.y = r4.y + (q4.y - r4.y); rsv.y = r4.y - q4.y; dq = q4.y - r4.y; ss = fmaf(dq, dq, ss);
      stv.z = r4.z + (q4.z - r4.z); rsv.z = r4.z - q4.z; dq = q4.z - r4.z; ss = fmaf(dq, dq, ss);
      stv.w = r4.w + (q4.w - r4.w); rsv.w = r4.w - q4.w; dq = q4.w - r4.w; ss = fmaf(dq, dq, ss);
      ((float4*)(out + ZQ_OFF  + zrow))[ln] = stv;
      ((float4*)(out + RES_OFF + zrow))[ln] = rsv;
    }
  }
  double dss = (double)ss;
  for (int o = 32; o; o >>= 1) dss += __shfl_down(dss, o, 64);
  if (ln == 0) wred[wv] = dss;
  __syncthreads();
  if (tid == 0) bss[wg] = wred[0] + wred[1] + wred[2] + wred[3];
}

// ---------------- K3: scalars (loss, perplexity) ----------------------------
__global__ void vqr_final(const int* __restrict__ counts,
                          const double* __restrict__ bss,
                          float* __restrict__ out) {
  __shared__ double red[256];
  const int t = threadIdx.x;
  double s = 0.0;
  for (int i = t; i < 1024; i += 256) s += bss[i];
  red[t] = s; __syncthreads();
  for (int s2 = 128; s2 > 0; s2 >>= 1) { if (t < s2) red[t] += red[t + s2]; __syncthreads(); }
  const double ssq = red[0];
  __syncthreads();
  double h = 0.0;
  for (int c = t; c < 1024; c += 256) {
    double p = (double)counts[c] / 131072.0;
    h += p * log(p + 1e-10);
  }
  red[t] = h; __syncthreads();
  for (int s2 = 128; s2 > 0; s2 >>= 1) { if (t < s2) red[t] += red[t + s2]; __syncthreads(); }
  if (t == 0) {
    out[LOSS_OFF] = (float)(0.25 * ssq / 33554432.0);
    out[PERP_OFF] = (float)exp(-red[0]);
  }
}

extern "C" void kernel_launch(void* const* d_in, const int* in_sizes, int n_in,
                              void* d_out, int out_size, void* d_ws, size_t ws_size,
                              hipStream_t stream) {
  // Bind inputs by SIZE: z has 33,554,432 elems, codebook 262,144.
  const float* z;
  const float* cb;
  if (in_sizes[0] == NR * DD) { z = (const float*)d_in[0]; cb = (const float*)d_in[1]; }
  else                        { cb = (const float*)d_in[0]; z = (const float*)d_in[1]; }

  float* out = (float*)d_out;
  char* ws = (char*)d_ws;
  int*            counts = (int*)(ws + WS_CNT);
  float*          c2n    = (float*)(ws + WS_C2N);
  double*         bssp   = (double*)(ws + WS_BSS);
  unsigned short* cbs    = (unsigned short*)(ws + WS_CBS);

  hipMemsetAsync(counts, 0, 4096, stream);
  vqr_c2<<<4, 256, 0, stream>>>(cb, c2n);
  vqr_cbsplit<<<128, 256, 0, stream>>>(cb, cbs);
  vqr_main<<<NR / 128, 256, 0, stream>>>(z, cb, cbs, c2n, out, counts, bssp);
  vqr_final<<<1, 256, 0, stream>>>(counts, bssp, out);
}

// Round 18
// 305.526 us; speedup vs baseline: 1.1284x; 1.0158x over previous
//
#include <hip/hip_runtime.h>
#include <math.h>

#define NR 131072
#define KC 1024
#define DD 256

// d_out element offsets (float32 elements)
#define ZQ_OFF  0
#define RES_OFF 33554432
#define IDX_OFF 67108864
#define LOSS_OFF 67239936
#define PERP_OFF 67239937

// ws byte offsets (total ~536 KB)
#define WS_CNT 0          // int[1024]
#define WS_C2N 4096       // float[1024]
#define WS_BSS 8192       // double[1024]
#define WS_CBS 16384      // ushort cbs hi-only: 64 tiles x 8KB = 512KB

#define MARG 5e-4f
#define CCAP 24

#define FM(x,y) __fmul_rn((x),(y))
#define FA(x,y) __fadd_rn((x),(y))

typedef __attribute__((ext_vector_type(8))) short bf16x8;
typedef __attribute__((ext_vector_type(4))) float f32x4;

static __device__ __forceinline__ unsigned short bf16h(float f) {
  unsigned int u = __float_as_uint(f);
  u += 0x7FFFu + ((u >> 16) & 1u);
  return (unsigned short)(u >> 16);
}

// ---- numpy f32 pairwise sum-of-squares, one 128-block (AVX512 tree) --------
static __device__ __forceinline__ float np_sumsq128(const float* __restrict__ q) {
  float lane[16];
#pragma unroll
  for (int l = 0; l < 16; l++) {
    float s0 = FM(q[l +   0], q[l +   0]);
    float s1 = FM(q[l +  16], q[l +  16]);
    float s2 = FM(q[l +  32], q[l +  32]);
    float s3 = FM(q[l +  48], q[l +  48]);
    float s4 = FM(q[l +  64], q[l +  64]);
    float s5 = FM(q[l +  80], q[l +  80]);
    float s6 = FM(q[l +  96], q[l +  96]);
    float s7 = FM(q[l + 112], q[l + 112]);
    lane[l] = FA(FA(FA(s0, s1), FA(s2, s3)), FA(FA(s4, s5), FA(s6, s7)));
  }
#pragma unroll
  for (int h = 8; h >= 1; h >>= 1)
#pragma unroll
    for (int l = 0; l < 8; l++)
      if (l < h) lane[l] = FA(lane[l], lane[l + h]);
  return lane[0];
}

static __device__ __forceinline__ float np_sumsq256(const float* __restrict__ p) {
  return FA(np_sumsq128(p), np_sumsq128(p + 128));
}

// ---------------- K1a: codebook c2 (numpy-replica f32) ----------------------
__global__ void vqs_c2(const float* __restrict__ cb, float* __restrict__ c2n) {
  const int code = blockIdx.x * 256 + threadIdx.x;
  if (code < KC) c2n[code] = np_sumsq256(cb + (size_t)code * DD);
}

// ---------------- K1b: codebook bf16 hi split, MFMA-granule layout ----------
// Tile t (16 codes) = 8KB = 512 granules of 16B. Granule gi within tile:
// kc=gi>>6, q=(gi>>4)&3, c=gi&15 holds bf16_hi(cb[t*16+c][kc*32+q*8+j]) j=0..7.
// A-frag load is lane-linear: byte addr = t*8192 + kc*1024 + lane*16, so one
// global_load_dwordx4 per (tile,kc) fetches a contiguous 1KB -> pure L2 stream.
__global__ void vqs_cbsplit(const float* __restrict__ cb,
                            unsigned short* __restrict__ cbs) {
  const int g  = blockIdx.x * 256 + threadIdx.x;   // 0..32767
  const int t  = g >> 9;
  const int gi = g & 511;
  const int kc = gi >> 6, q = (gi >> 4) & 3, c = gi & 15;
  const float* src = cb + (size_t)(t * 16 + c) * DD + kc * 32 + q * 8;
  unsigned int w[4];
#pragma unroll
  for (int p = 0; p < 4; p++)
    w[p] = (unsigned int)bf16h(src[p * 2]) |
           ((unsigned int)bf16h(src[p * 2 + 1]) << 16);
  *(uint4*)(cbs + (size_t)g * 8) = make_uint4(w[0], w[1], w[2], w[3]);
}

// ---------------- K2: wave-decoupled MFMA screen + exact-np rescore ---------
// As round 17 (proven numerics), but ZERO cross-wave barriers until the final
// loss reduction: all intermediate LDS state (ccnt/ccode/cd/m1row/z2s/rowidx)
// is wave-private by construction; c2l is loaded redundantly by every wave
// (benign identical-value race). Each of the 16 waves/CU runs its own
// prologue->main->finalize->epilogue pipeline and drifts freely, so HBM, L2
// and MFMA phases of different waves overlap instead of bursting in lockstep.
__global__ __launch_bounds__(256, 4) void vqs_main(
    const float* __restrict__ z, const float* __restrict__ cb,
    const unsigned short* __restrict__ cbs,
    const float* __restrict__ c2n,
    float* __restrict__ out, int* __restrict__ counts,
    double* __restrict__ bss) {
  __shared__ unsigned short ccode[128][CCAP];           //  6 KB
  __shared__ float cd[128][CCAP];                       // 12 KB
  __shared__ int ccnt[128];
  __shared__ float m1row[128];
  __shared__ float z2s[128];
  __shared__ int rowidx[128];
  __shared__ __align__(16) float c2l[1024];             //  4 KB
  __shared__ double wred[4];

  const int tid = threadIdx.x, wg = blockIdx.x;
  const int wv = tid >> 6, ln = tid & 63;
  const int rl = ln & 15;           // row within group
  const int qk = ln >> 4;           // k-octet / code-quad selector
  const int rowg0 = wg * 128 + wv * 32 + rl;      // group-0 global row

  // ---- c2 into LDS: every wave loads ALL of it (benign same-value race) ----
#pragma unroll
  for (int i = 0; i < 4; i++)
    ((float4*)c2l)[i * 64 + ln] = ((const float4*)c2n)[i * 64 + ln];
  // ---- per-wave candidate-count init (rows wv*32..wv*32+31 are wave-own) ---
  if (ln < 32) ccnt[wv * 32 + ln] = 0;

  // ---- build z hi-fragments in registers for both row-groups ----
  bf16x8 zH0[8], zH1[8];
#pragma unroll
  for (int kc = 0; kc < 8; kc++) {
    const float4* p0 = (const float4*)(z + (size_t)rowg0 * DD + kc * 32 + qk * 8);
    const float4* p1 = (const float4*)(z + (size_t)(rowg0 + 16) * DD + kc * 32 + qk * 8);
    const float4 a0 = p0[0], b0 = p0[1];
    const float4 a1 = p1[0], b1 = p1[1];
    zH0[kc][0] = (short)bf16h(a0.x); zH0[kc][1] = (short)bf16h(a0.y);
    zH0[kc][2] = (short)bf16h(a0.z); zH0[kc][3] = (short)bf16h(a0.w);
    zH0[kc][4] = (short)bf16h(b0.x); zH0[kc][5] = (short)bf16h(b0.y);
    zH0[kc][6] = (short)bf16h(b0.z); zH0[kc][7] = (short)bf16h(b0.w);
    zH1[kc][0] = (short)bf16h(a1.x); zH1[kc][1] = (short)bf16h(a1.y);
    zH1[kc][2] = (short)bf16h(a1.z); zH1[kc][3] = (short)bf16h(a1.w);
    zH1[kc][4] = (short)bf16h(b1.x); zH1[kc][5] = (short)bf16h(b1.y);
    zH1[kc][6] = (short)bf16h(b1.z); zH1[kc][7] = (short)bf16h(b1.w);
  }

  // ---- z2 (exact np AVX512 tree), wave-own rows only ----
  {
    const int gg = ln >> 4, l = ln & 15;
#pragma unroll 1
    for (int g4 = 0; g4 < 8; g4++) {
      const int rlcl = wv * 32 + g4 * 4 + gg;
      const float* q = z + (size_t)(wg * 128 + rlcl) * DD;
      float blk[2];
#pragma unroll
      for (int b = 0; b < 2; b++) {
        const float* qq = q + b * 128;
        const float s0 = FM(qq[l +   0], qq[l +   0]);
        const float s1 = FM(qq[l +  16], qq[l +  16]);
        const float s2 = FM(qq[l +  32], qq[l +  32]);
        const float s3 = FM(qq[l +  48], qq[l +  48]);
        const float s4 = FM(qq[l +  64], qq[l +  64]);
        const float s5 = FM(qq[l +  80], qq[l +  80]);
        const float s6 = FM(qq[l +  96], qq[l +  96]);
        const float s7 = FM(qq[l + 112], qq[l + 112]);
        float v = FA(FA(FA(s0, s1), FA(s2, s3)), FA(FA(s4, s5), FA(s6, s7)));
#pragma unroll
        for (int h = 8; h >= 1; h >>= 1) v = FA(v, __shfl_down(v, h, 16));
        blk[b] = v;
      }
      if (l == 0) z2s[rlcl] = FA(blk[0], blk[1]);
    }
  }

  const float z2v0 = z2s[wv * 32 + rl];
  const float z2v1 = z2s[wv * 32 + rl + 16];
  const int rw0 = wv * 32 + rl;

  float m10 = INFINITY, m11 = INFINITY;
#pragma unroll 2
  for (int t = 0; t < 64; t++) {
    // direct global->register A-fragments (L2-resident cbs, coalesced 1KB/load)
    bf16x8 aH[8];
#pragma unroll
    for (int kc = 0; kc < 8; kc++)
      aH[kc] = *(const bf16x8*)(cbs + (size_t)t * 4096 + kc * 512 + ln * 8);

    f32x4 accA = {0.f, 0.f, 0.f, 0.f}, accB = accA;
#pragma unroll
    for (int kc = 0; kc < 8; kc++) {
      accA = __builtin_amdgcn_mfma_f32_16x16x32_bf16(aH[kc], zH0[kc], accA, 0, 0, 0);
      accB = __builtin_amdgcn_mfma_f32_16x16x32_bf16(aH[kc], zH1[kc], accB, 0, 0, 0);
    }
    // fold: lane covers codes t*16 + qk*4 + r, rows (group0, group1)
    const float4 c2v4 = *(const float4*)&c2l[t * 16 + qk * 4];
    float dh0[4], dh1[4];
#pragma unroll
    for (int r = 0; r < 4; r++) {
      const float c2v = r == 0 ? c2v4.x : r == 1 ? c2v4.y : r == 2 ? c2v4.z : c2v4.w;
      dh0[r] = z2v0 - 2.f * accA[r] + c2v;
      dh1[r] = z2v1 - 2.f * accB[r] + c2v;
      m10 = fminf(m10, dh0[r]);
      m11 = fminf(m11, dh1[r]);
    }
    m10 = fminf(m10, __shfl_xor(m10, 16));
    m10 = fminf(m10, __shfl_xor(m10, 32));
    m11 = fminf(m11, __shfl_xor(m11, 16));
    m11 = fminf(m11, __shfl_xor(m11, 32));
#pragma unroll
    for (int r = 0; r < 4; r++) {
      if (dh0[r] <= m10 + MARG) {
        const int s = atomicAdd(&ccnt[rw0], 1);
        if (s < CCAP) {
          ccode[rw0][s] = (unsigned short)(t * 16 + qk * 4 + r);
          cd[rw0][s] = dh0[r];
        }
      }
      if (dh1[r] <= m11 + MARG) {
        const int s = atomicAdd(&ccnt[rw0 + 16], 1);
        if (s < CCAP) {
          ccode[rw0 + 16][s] = (unsigned short)(t * 16 + qk * 4 + r);
          cd[rw0 + 16][s] = dh1[r];
        }
      }
    }
  }

  if (qk == 0) { m1row[rw0] = m10; m1row[rw0 + 16] = m11; }
  // (no barrier: m1row/candidates are wave-own)

  // ---- finalize (wave-own rows: lanes 0..31 -> rows wv*32+ln) ----
  if (ln < 32) {
    const int rwl = wv * 32 + ln;
    const int row = wg * 128 + rwl;
    const float mf = m1row[rwl] + MARG;
    const int nc = ccnt[rwl];
    int best;
    if (nc > CCAP) {             // overflow (P~0): full exact np scan
      const float* zr = z + (size_t)row * DD;
      const float z2r = z2s[rwl];
      float db = INFINITY; best = 0;
      for (int c = 0; c < KC; c++) {
        const float* cr = cb + (size_t)c * DD;
        float dot = 0.f;
#pragma unroll 8
        for (int k = 0; k < DD; k++) dot = __fmaf_rn(zr[k], cr[k], dot);
        const float t1 = 2.0f * dot;
        const float d = FA(FA(z2r, -t1), c2l[c]);
        if (d < db) { db = d; best = c; }          // ascending c: first-min
      }
    } else {
      int kept = 0, kcode = 0;
      for (int s = 0; s < nc; s++)
        if (cd[rwl][s] <= mf) { kept++; kcode = ccode[rwl][s]; }
      if (kept == 1) best = kcode;
      else {
        const float* zr = z + (size_t)row * DD;
        const float z2r = z2s[rwl];
        float db = INFINITY; int bi = 0x7FFFFFFF;
        for (int s = 0; s < nc; s++) {
          if (cd[rwl][s] > mf) continue;
          const int c = ccode[rwl][s];
          const float* cr = cb + (size_t)c * DD;
          float dot = 0.f;
#pragma unroll 8
          for (int k = 0; k < DD; k++) dot = __fmaf_rn(zr[k], cr[k], dot);
          const float t1 = 2.0f * dot;
          const float d = FA(FA(z2r, -t1), c2l[c]);   // exact np-f32 d
          if (d < db || (d == db && c < bi)) { db = d; bi = c; }
        }
        best = bi;
      }
    }
    rowidx[rwl] = best;
    atomicAdd(&counts[best], 1);
    out[IDX_OFF + row] = (float)best;
  }
  // (no barrier: rowidx for this wave's rows written by this wave)

  // ---- gather + zq_st / residual: one wave per row, 8-row batches ----
  float ss = 0.f;
#pragma unroll 1
  for (int g = 0; g < 32; g += 8) {
    float4 r4b[8], q4b[8];
#pragma unroll
    for (int u = 0; u < 8; u++) {
      const int rlcl = wv * 32 + g + u;
      const size_t zrow = (size_t)(wg * 128 + rlcl) * DD;
      r4b[u] = ((const float4*)(z + zrow))[ln];
      q4b[u] = ((const float4*)(cb + (size_t)rowidx[rlcl] * DD))[ln];
    }
#pragma unroll
    for (int u = 0; u < 8; u++) {
      const int rlcl = wv * 32 + g + u;
      const size_t zrow = (size_t)(wg * 128 + rlcl) * DD;
      const float4 r4 = r4b[u];
      const float4 q4 = q4b[u];
      float4 stv, rsv; float dq;
      stv.x = r4.x + (q4.x - r4.x); rsv.x = r4.x - q4.x; dq = q4.x - r4.x; ss = fmaf(dq, dq, ss);
      stv.y = r4.y + (q4.y - r4.y); rsv.y = r4.y - q4.y; dq = q4.y - r4.y; ss = fmaf(dq, dq, ss);
      stv.z = r4.z + (q4.z - r4.z); rsv.z = r4.z - q4.z; dq = q4.z - r4.z; ss = fmaf(dq, dq, ss);
      stv.w = r4.w + (q4.w - r4.w); rsv.w = r4.w - q4.w; dq = q4.w - r4.w; ss = fmaf(dq, dq, ss);
      ((float4*)(out + ZQ_OFF  + zrow))[ln] = stv;
      ((float4*)(out + RES_OFF + zrow))[ln] = rsv;
    }
  }
  double dss = (double)ss;
  for (int o = 32; o; o >>= 1) dss += __shfl_down(dss, o, 64);
  if (ln == 0) wred[wv] = dss;
  __syncthreads();                 // ONLY cross-wave sync: loss reduction
  if (tid == 0) bss[wg] = wred[0] + wred[1] + wred[2] + wred[3];
}

// ---------------- K3: scalars (loss, perplexity) ----------------------------
__global__ void vqs_final(const int* __restrict__ counts,
                          const double* __restrict__ bss,
                          float* __restrict__ out) {
  __shared__ double red[256];
  const int t = threadIdx.x;
  double s = 0.0;
  for (int i = t; i < 1024; i += 256) s += bss[i];
  red[t] = s; __syncthreads();
  for (int s2 = 128; s2 > 0; s2 >>= 1) { if (t < s2) red[t] += red[t + s2]; __syncthreads(); }
  const double ssq = red[0];
  __syncthreads();
  double h = 0.0;
  for (int c = t; c < 1024; c += 256) {
    double p = (double)counts[c] / 131072.0;
    h += p * log(p + 1e-10);
  }
  red[t] = h; __syncthreads();
  for (int s2 = 128; s2 > 0; s2 >>= 1) { if (t < s2) red[t] += red[t + s2]; __syncthreads(); }
  if (t == 0) {
    out[LOSS_OFF] = (float)(0.25 * ssq / 33554432.0);
    out[PERP_OFF] = (float)exp(-red[0]);
  }
}

extern "C" void kernel_launch(void* const* d_in, const int* in_sizes, int n_in,
                              void* d_out, int out_size, void* d_ws, size_t ws_size,
                              hipStream_t stream) {
  // Bind inputs by SIZE: z has 33,554,432 elems, codebook 262,144.
  const float* z;
  const float* cb;
  if (in_sizes[0] == NR * DD) { z = (const float*)d_in[0]; cb = (const float*)d_in[1]; }
  else                        { cb = (const float*)d_in[0]; z = (const float*)d_in[1]; }

  float* out = (float*)d_out;
  char* ws = (char*)d_ws;
  int*            counts = (int*)(ws + WS_CNT);
  float*          c2n    = (float*)(ws + WS_C2N);
  double*         bssp   = (double*)(ws + WS_BSS);
  unsigned short* cbs    = (unsigned short*)(ws + WS_CBS);

  hipMemsetAsync(counts, 0, 4096, stream);
  vqs_c2<<<4, 256, 0, stream>>>(cb, c2n);
  vqs_cbsplit<<<128, 256, 0, stream>>>(cb, cbs);
  vqs_main<<<NR / 128, 256, 0, stream>>>(z, cb, cbs, c2n, out, counts, bssp);
  vqs_final<<<1, 256, 0, stream>>>(counts, bssp, out);
}